// Round 6
// baseline (367.254 us; speedup 1.0000x reference)
//
#include <hip/hip_runtime.h>
#include <math.h>

#define CLASSNUM 70722
#define BATCH 512
#define EMBD 512
#define M_C 0.4f
#define H_C 0.333f
#define S_C 64.0f
#define EPS_C 0.001f
#define PI_F 3.14159265358979f

typedef __bf16 bf16_t;
typedef __bf16 bf16x4 __attribute__((ext_vector_type(4)));
typedef __bf16 bf16x8 __attribute__((ext_vector_type(8)));
typedef float f32x4 __attribute__((ext_vector_type(4)));

__device__ __forceinline__ float clampf(float x, float lo, float hi) {
    return fminf(fmaxf(x, lo), hi);
}

// ---------------------------------------------------------------------------
// prep: block 0 computes margin_scaler msw[512]; blocks 1..128 convert the
// embeddings to bf16 in MFMA-fragment order (fragment F(kt,rg) = rows
// [rg*16,rg*16+16) x k [kt*32,kt*32+32), 1 KB contiguous, lane-ordered).
// The old 512-block label-column gather (262K random HBM accesses, serialized
// before gemm) is GONE -- moved into the gemm blocks where it hides.
// ---------------------------------------------------------------------------
__global__ __launch_bounds__(256) void prep_kernel(
    const float* __restrict__ emb, const float* __restrict__ norms,
    const float* __restrict__ csn, bf16_t* __restrict__ Aws,
    float* __restrict__ msw)
{
    __shared__ float sred[256];
    const int tid = threadIdx.x;
    if (blockIdx.x == 0) {
        float s0, s1;
        {
            float sn = clampf(norms[tid], 0.001f, 100.0f);
            sn = sn / (csn[tid] + 0.001f);
            s0 = clampf(sn, 0.001f, 100.0f);
        }
        {
            float sn = clampf(norms[tid + 256], 0.001f, 100.0f);
            sn = sn / (csn[tid + 256] + 0.001f);
            s1 = clampf(sn, 0.001f, 100.0f);
        }
        sred[tid] = s0 + s1;
        __syncthreads();
        for (int off = 128; off > 0; off >>= 1) {
            if (tid < off) sred[tid] += sred[tid + off];
            __syncthreads();
        }
        const float mean = sred[0] * (1.0f / 512.0f);
        __syncthreads();
        const float d0 = s0 - mean, d1 = s1 - mean;
        sred[tid] = d0 * d0 + d1 * d1;
        __syncthreads();
        for (int off = 128; off > 0; off >>= 1) {
            if (tid < off) sred[tid] += sred[tid + off];
            __syncthreads();
        }
        const float stdv = sqrtf(sred[0] * (1.0f / 511.0f));  // ddof=1
        const float inv = 1.0f / (stdv + EPS_C);
        msw[tid]       = clampf(d0 * inv * H_C, -1.0f, 1.0f);
        msw[tid + 256] = clampf(d1 * inv * H_C, -1.0f, 1.0f);
    } else {
        const int G = (blockIdx.x - 1) * 256 + tid;   // granule id, 0..32767
        const int kt = G >> 11;
        const int rem = G & 2047;
        const int rg = rem >> 6;
        const int lane = rem & 63;
        const int row = rg * 16 + (lane & 15);
        const int k0 = kt * 32 + (lane >> 4) * 8;
        const float* src = emb + row * EMBD + k0;
        const float4 v0 = *(const float4*)src;
        const float4 v1 = *(const float4*)(src + 4);
        bf16x8 bw;
        bw[0] = (bf16_t)v0.x; bw[1] = (bf16_t)v0.y;
        bw[2] = (bf16_t)v0.z; bw[3] = (bf16_t)v0.w;
        bw[4] = (bf16_t)v1.x; bw[5] = (bf16_t)v1.y;
        bw[6] = (bf16_t)v1.z; bw[7] = (bf16_t)v1.w;
        *(bf16x8*)(Aws + (size_t)G * 8) = bw;         // coalesced 16 B store
    }
}

// ---------------------------------------------------------------------------
// gemm v6 = v3 (the 117 us best) + three deltas:
//  (1) A fragments loaded ONE STEP AHEAD, in place, right after the MFMA that
//      consumed them (WAR register reuse -> zero extra VGPRs, ~1 step of
//      latency lead for the L2 A-reads instead of 0).
//  (2) exact-fp32 label phase fused: each block scans its 512 labels; for
//      labels inside its 64-col window (~0.46/block) one wave re-reads that
//      K column in fp32, computes the margin formula with msw, stores to
//      lo_s -- the epilogue substitution (labc==col) does the rest.
//      This deletes the serial 512-block gather kernel entirely.
//  (3) nontemporal epilogue stores (don't evict K from L2/L3 with 145 MB
//      of streaming writes).
// Geometry unchanged: MT=512 x NT=64, 8 waves, B staged cooperatively 2 steps
// ahead via regs->LDS, raw s_barrier + lgkmcnt(0) only (loads cross barriers).
// __launch_bounds__(512,4) caps regs at 128 -> 2 blocks/CU.
// ---------------------------------------------------------------------------

#define LOADB4(t, dst) do {                                             \
    const size_t ko_ = (size_t)((t) * 32) * CLASSNUM;                   \
    _Pragma("unroll")                                                   \
    for (int j_ = 0; j_ < 4; ++j_)                                      \
        dst[j_] = bp[ko_ + (size_t)j_ * CLASSNUM];                      \
} while (0)

#define LOADA4(t, af) do {                                              \
    const bf16x8* ap_ = (const bf16x8*)Aws                              \
        + (((t) * 32 + wave * 4) * 64 + lane);                          \
    _Pragma("unroll")                                                   \
    for (int mi_ = 0; mi_ < 4; ++mi_) af[mi_] = ap_[mi_ * 64];          \
} while (0)

#define CVTW(src, buf) do {                                             \
    bf16x4 w_;                                                          \
    _Pragma("unroll")                                                   \
    for (int j_ = 0; j_ < 4; ++j_) {                                    \
        const float v_ = src[j_];                                       \
        ssq = fmaf(v_, v_, ssq);                                        \
        w_[j_] = (bf16_t)v_;                                            \
    }                                                                   \
    *(bf16x4*)&Blds[buf][c * 40 + kg * 4] = w_;                         \
} while (0)

#define MFMA16(af, buf) do {                                            \
    bf16x8 bfr_[4];                                                     \
    _Pragma("unroll")                                                   \
    for (int ni_ = 0; ni_ < 4; ++ni_)                                   \
        bfr_[ni_] = *(const bf16x8*)                                    \
            &Blds[buf][(ni_ * 16 + r16) * 40 + quad * 8];               \
    __builtin_amdgcn_s_setprio(1);                                      \
    _Pragma("unroll")                                                   \
    for (int mi_ = 0; mi_ < 4; ++mi_)                                   \
        _Pragma("unroll")                                               \
        for (int ni_ = 0; ni_ < 4; ++ni_)                               \
            acc[mi_][ni_] = __builtin_amdgcn_mfma_f32_16x16x32_bf16(    \
                af[mi_], bfr_[ni_], acc[mi_][ni_], 0, 0, 0);            \
    __builtin_amdgcn_s_setprio(0);                                      \
} while (0)

#define BARRIER() do {                                                  \
    asm volatile("s_waitcnt lgkmcnt(0)" ::: "memory");                  \
    __builtin_amdgcn_s_barrier();                                       \
} while (0)

__global__ __launch_bounds__(512, 4) void gemm_kernel(
    const bf16_t* __restrict__ Aws, const float* __restrict__ Kmat,
    const float* __restrict__ emb, const int* __restrict__ label,
    const float* __restrict__ msw, float* __restrict__ out)
{
    __shared__ bf16_t Blds[2][64 * 40];     // padded stride 40
    __shared__ float red[512];
    __shared__ float invn_s[64];
    __shared__ int   lab_s[BATCH];
    __shared__ float lo_s[BATCH];

    const int tid  = threadIdx.x;
    const int lane = tid & 63;
    const int wave = tid >> 6;              // 0..7
    const int r16  = lane & 15;
    const int quad = lane >> 4;

    // bijective XCD swizzle (nwg=1106 = 8*138+2)
    const int nwg = (CLASSNUM + 63) / 64;
    const int q_ = nwg >> 3, r_ = nwg & 7;
    const int xcd = blockIdx.x & 7, idx = blockIdx.x >> 3;
    const int nb = (xcd < r_) ? (xcd * (q_ + 1) + idx)
                              : (r_ * (q_ + 1) + (xcd - r_) * q_ + idx);
    const int n0 = nb * 64;

    lab_s[tid] = label[tid];

    // B cooperative-load ownership: col c (0..63), k-group kg (0..7) of 4 k.
    const int c  = tid & 63;
    const int kg = tid >> 6;
    int cg = n0 + c;
    if (cg >= CLASSNUM) cg = CLASSNUM - 1;   // clamp; stores are guarded
    const float* bp = Kmat + (size_t)(kg * 4) * CLASSNUM + cg;

    f32x4 acc[4][4];
    const f32x4 zero = {0.0f, 0.0f, 0.0f, 0.0f};
#pragma unroll
    for (int i = 0; i < 4; ++i)
#pragma unroll
        for (int j = 0; j < 4; ++j) acc[i][j] = zero;
    float ssq = 0.0f;

    float bv0[4], bv1[4];
    bf16x8 af[4];

    // ---- prologue: B(0)->bv0, B(1)->bv1, A(0)->af, stage B(0)->Blds[0] ----
    LOADB4(0, bv0);
    LOADB4(1, bv1);
    LOADA4(0, af);
    CVTW(bv0, 0);
    BARRIER();

    // ---- K loop, hand-unrolled x2.  af holds A(it), reloaded in place
    // (A(it+1)) right after the MFMA consumes it -> one step of lead. ----
#pragma unroll 1
    for (int p = 0; p < 8; ++p) {
        {   // it = 2p: MFMA on Blds[0]; stage B(2p+1) -> Blds[1]
            if (p < 7) LOADB4(2 * p + 2, bv0);
            MFMA16(af, 0);
            LOADA4(2 * p + 1, af);
            CVTW(bv1, 1);
            BARRIER();
        }
        {   // it = 2p+1: MFMA on Blds[1]; stage B(2p+2) -> Blds[0]
            if (p < 7) LOADB4(2 * p + 3, bv1);
            MFMA16(af, 1);
            if (p < 7) {
                LOADA4(2 * p + 2, af);
                CVTW(bv0, 0);
            }
            BARRIER();
        }
    }

    // ---- column inverse norms: 8 k-partials per column (kg groups) ----
    red[tid] = ssq;
    __syncthreads();
    if (tid < 64) {
        float s = 0.0f;
#pragma unroll
        for (int g = 0; g < 8; ++g) s += red[tid + g * 64];
        invn_s[tid] = (s > 0.0f) ? (1.0f / sqrtf(s)) : 0.0f;
    }

    // ---- fused exact label phase: each wave scans 64 rows; for labels in
    // this block's window (~0.46 per block), recompute the fp32 dot + column
    // norm + margin formula and park it in lo_s for the epilogue.
#pragma unroll 1
    for (int b = wave; b < BATCH; b += 8) {
        const int lc = lab_s[b];
        if (lc >= n0 && lc < n0 + 64) {          // wave-uniform branch
            const float* col = Kmat + lc;
            const float* e = emb + b * EMBD;
            float dot = 0.0f, ss = 0.0f;
#pragma unroll
            for (int k = lane; k < EMBD; k += 64) {
                const float kv = col[(size_t)k * CLASSNUM];
                dot = fmaf(e[k], kv, dot);
                ss  = fmaf(kv, kv, ss);
            }
            for (int off = 32; off > 0; off >>= 1) {
                dot += __shfl_down(dot, off);
                ss  += __shfl_down(ss, off);
            }
            if (lane == 0) {
                float cc = dot / sqrtf(ss);
                cc = clampf(cc, -1.0f + EPS_C, 1.0f - EPS_C);
                const float msv = msw[b];
                float th = acosf(cc) - M_C * msv;
                th = clampf(th, EPS_C, PI_F - EPS_C);
                lo_s[b] = (cosf(th) - (M_C + M_C * msv)) * S_C;
            }
        }
    }
    __syncthreads();

    // ---- epilogue: out = S * clip(cosine); label entries substituted;
    // nontemporal stores keep K resident in L2/L3. ----
#pragma unroll
    for (int mi = 0; mi < 4; ++mi) {
#pragma unroll
        for (int rr = 0; rr < 4; ++rr) {
            const int row = wave * 64 + mi * 16 + quad * 4 + rr;
            const int labc = lab_s[row];
            const float lov = lo_s[row];
            float* orow = out + (size_t)row * CLASSNUM;
#pragma unroll
            for (int ni = 0; ni < 4; ++ni) {
                const int col_loc = ni * 16 + r16;
                const int col = n0 + col_loc;
                if (col < CLASSNUM) {
                    const float cc = clampf(acc[mi][ni][rr] * invn_s[col_loc],
                                            -1.0f + EPS_C, 1.0f - EPS_C);
                    float v = cc * S_C;
                    if (labc == col) v = lov;
                    __builtin_nontemporal_store(v, &orow[col]);
                }
            }
        }
    }
}

extern "C" void kernel_launch(void* const* d_in, const int* in_sizes, int n_in,
                              void* d_out, int out_size, void* d_ws, size_t ws_size,
                              hipStream_t stream)
{
    const float* emb   = (const float*)d_in[0];
    const float* norms = (const float*)d_in[1];
    const int*   label = (const int*)d_in[2];
    const float* csn   = (const float*)d_in[3];
    const float* kmat  = (const float*)d_in[4];
    float* out = (float*)d_out;

    // workspace: [A bf16 fragment-tiled 512x512 | msw 512]
    const size_t A_BYTES = (size_t)BATCH * EMBD * sizeof(bf16_t);  // 524288
    if (ws_size < A_BYTES + 4096) return;
    bf16_t* Aws = (bf16_t*)d_ws;
    float* msw  = (float*)((char*)d_ws + A_BYTES);

    prep_kernel<<<129, 256, 0, stream>>>(emb, norms, csn, Aws, msw);
    const int nblk = (CLASSNUM + 63) / 64;   // 1106
    gemm_kernel<<<nblk, 512, 0, stream>>>(Aws, kmat, emb, label, msw, out);
}

// Round 7
// 325.038 us; speedup vs baseline: 1.1299x; 1.1299x over previous
//
#include <hip/hip_runtime.h>
#include <math.h>

#define CLASSNUM 70722
#define BATCH 512
#define EMBD 512
#define M_C 0.4f
#define H_C 0.333f
#define S_C 64.0f
#define EPS_C 0.001f
#define PI_F 3.14159265358979f

typedef __bf16 bf16_t;
typedef __bf16 bf16x4 __attribute__((ext_vector_type(4)));
typedef __bf16 bf16x8 __attribute__((ext_vector_type(8)));
typedef float f32x4 __attribute__((ext_vector_type(4)));

__device__ __forceinline__ float clampf(float x, float lo, float hi) {
    return fminf(fmaxf(x, lo), hi);
}

// ---------------------------------------------------------------------------
// prep: block 0 computes margin_scaler msw[512]; blocks 1..128 convert the
// embeddings to bf16 in MFMA-fragment order (fragment F(kt,rg) = rows
// [rg*16,rg*16+16) x k [kt*32,kt*32+32), 1 KB contiguous, lane-ordered).
// ---------------------------------------------------------------------------
__global__ __launch_bounds__(256) void prep_kernel(
    const float* __restrict__ emb, const float* __restrict__ norms,
    const float* __restrict__ csn, bf16_t* __restrict__ Aws,
    float* __restrict__ msw)
{
    __shared__ float sred[256];
    const int tid = threadIdx.x;
    if (blockIdx.x == 0) {
        float s0, s1;
        {
            float sn = clampf(norms[tid], 0.001f, 100.0f);
            sn = sn / (csn[tid] + 0.001f);
            s0 = clampf(sn, 0.001f, 100.0f);
        }
        {
            float sn = clampf(norms[tid + 256], 0.001f, 100.0f);
            sn = sn / (csn[tid + 256] + 0.001f);
            s1 = clampf(sn, 0.001f, 100.0f);
        }
        sred[tid] = s0 + s1;
        __syncthreads();
        for (int off = 128; off > 0; off >>= 1) {
            if (tid < off) sred[tid] += sred[tid + off];
            __syncthreads();
        }
        const float mean = sred[0] * (1.0f / 512.0f);
        __syncthreads();
        const float d0 = s0 - mean, d1 = s1 - mean;
        sred[tid] = d0 * d0 + d1 * d1;
        __syncthreads();
        for (int off = 128; off > 0; off >>= 1) {
            if (tid < off) sred[tid] += sred[tid + off];
            __syncthreads();
        }
        const float stdv = sqrtf(sred[0] * (1.0f / 511.0f));  // ddof=1
        const float inv = 1.0f / (stdv + EPS_C);
        msw[tid]       = clampf(d0 * inv * H_C, -1.0f, 1.0f);
        msw[tid + 256] = clampf(d1 * inv * H_C, -1.0f, 1.0f);
    } else {
        const int G = (blockIdx.x - 1) * 256 + tid;   // granule id, 0..32767
        const int kt = G >> 11;
        const int rem = G & 2047;
        const int rg = rem >> 6;
        const int lane = rem & 63;
        const int row = rg * 16 + (lane & 15);
        const int k0 = kt * 32 + (lane >> 4) * 8;
        const float* src = emb + row * EMBD + k0;
        const float4 v0 = *(const float4*)src;
        const float4 v1 = *(const float4*)(src + 4);
        bf16x8 bw;
        bw[0] = (bf16_t)v0.x; bw[1] = (bf16_t)v0.y;
        bw[2] = (bf16_t)v0.z; bw[3] = (bf16_t)v0.w;
        bw[4] = (bf16_t)v1.x; bw[5] = (bf16_t)v1.y;
        bw[6] = (bf16_t)v1.z; bw[7] = (bf16_t)v1.w;
        *(bf16x8*)(Aws + (size_t)G * 8) = bw;         // coalesced 16 B store
    }
}

// ---------------------------------------------------------------------------
// gemm v7 = v3 (117 us best) + label-fusion, with the vmcnt queue discipline
// made explicit and strict:
//   INVARIANT: at any wait point, the load being waited on must be the OLDEST
//   outstanding VMEM op (vmcnt drains in issue order; waiting on a younger
//   load forces all older loads complete).
//   Per sub-iter:  [MFMA(af=A(it), Blds[buf])]   <- waits A(it), the oldest
//                  [LOADA(it+1) -> af in-place]  <- WAR reuse, 0 extra VGPR;
//                                                   now 1 full step of lead
//                  [LOADB(it+2)]                 <- youngest, 2-step lead
//                  [CVT B(it+1) -> Blds[buf^1]]  <- waits B(it+1): older than
//                                                   A(it+1)/B(it+2), forces
//                                                   only itself
//                  [lgkmcnt(0); s_barrier]       <- loads cross the barrier
// v6's mistake (A issued AFTER B(it+2) -> MFMA wait forced 1-step-old B) and
// v6's NT stores (WRITE_SIZE 148->251 MB partial-line amplification) are
// both reverted.  64 VGPR + 64 acc = 128 -> 4 waves/SIMD, 2 blocks/CU.
// ---------------------------------------------------------------------------

#define LOADB4(t, dst) do {                                             \
    const size_t ko_ = (size_t)((t) * 32) * CLASSNUM;                   \
    _Pragma("unroll")                                                   \
    for (int j_ = 0; j_ < 4; ++j_)                                      \
        dst[j_] = bp[ko_ + (size_t)j_ * CLASSNUM];                      \
} while (0)

#define LOADA4(t, af) do {                                              \
    const bf16x8* ap_ = (const bf16x8*)Aws                              \
        + (((t) * 32 + wave * 4) * 64 + lane);                          \
    _Pragma("unroll")                                                   \
    for (int mi_ = 0; mi_ < 4; ++mi_) af[mi_] = ap_[mi_ * 64];          \
} while (0)

#define CVTW(src, buf) do {                                             \
    bf16x4 w_;                                                          \
    _Pragma("unroll")                                                   \
    for (int j_ = 0; j_ < 4; ++j_) {                                    \
        const float v_ = src[j_];                                       \
        ssq = fmaf(v_, v_, ssq);                                        \
        w_[j_] = (bf16_t)v_;                                            \
    }                                                                   \
    *(bf16x4*)&Blds[buf][c * 40 + kg * 4] = w_;                         \
} while (0)

#define MFMA16(af, buf) do {                                            \
    bf16x8 bfr_[4];                                                     \
    _Pragma("unroll")                                                   \
    for (int ni_ = 0; ni_ < 4; ++ni_)                                   \
        bfr_[ni_] = *(const bf16x8*)                                    \
            &Blds[buf][(ni_ * 16 + r16) * 40 + quad * 8];               \
    __builtin_amdgcn_s_setprio(1);                                      \
    _Pragma("unroll")                                                   \
    for (int mi_ = 0; mi_ < 4; ++mi_)                                   \
        _Pragma("unroll")                                               \
        for (int ni_ = 0; ni_ < 4; ++ni_)                               \
            acc[mi_][ni_] = __builtin_amdgcn_mfma_f32_16x16x32_bf16(    \
                af[mi_], bfr_[ni_], acc[mi_][ni_], 0, 0, 0);            \
    __builtin_amdgcn_s_setprio(0);                                      \
} while (0)

#define BARRIER() do {                                                  \
    asm volatile("s_waitcnt lgkmcnt(0)" ::: "memory");                  \
    __builtin_amdgcn_s_barrier();                                       \
} while (0)

__global__ __launch_bounds__(512, 4) void gemm_kernel(
    const bf16_t* __restrict__ Aws, const float* __restrict__ Kmat,
    const float* __restrict__ emb, const int* __restrict__ label,
    const float* __restrict__ msw, float* __restrict__ out)
{
    __shared__ bf16_t Blds[2][64 * 40];     // padded stride 40
    __shared__ float red[512];
    __shared__ float invn_s[64];
    __shared__ int   lab_s[BATCH];
    __shared__ float lo_s[BATCH];

    const int tid  = threadIdx.x;
    const int lane = tid & 63;
    const int wave = tid >> 6;              // 0..7
    const int r16  = lane & 15;
    const int quad = lane >> 4;

    // bijective XCD swizzle (nwg=1106 = 8*138+2)
    const int nwg = (CLASSNUM + 63) / 64;
    const int q_ = nwg >> 3, r_ = nwg & 7;
    const int xcd = blockIdx.x & 7, idx = blockIdx.x >> 3;
    const int nb = (xcd < r_) ? (xcd * (q_ + 1) + idx)
                              : (r_ * (q_ + 1) + (xcd - r_) * q_ + idx);
    const int n0 = nb * 64;

    lab_s[tid] = label[tid];

    // B cooperative-load ownership: col c (0..63), k-group kg (0..7) of 4 k.
    const int c  = tid & 63;
    const int kg = tid >> 6;
    int cg = n0 + c;
    if (cg >= CLASSNUM) cg = CLASSNUM - 1;   // clamp; stores are guarded
    const float* bp = Kmat + (size_t)(kg * 4) * CLASSNUM + cg;

    f32x4 acc[4][4];
    const f32x4 zero = {0.0f, 0.0f, 0.0f, 0.0f};
#pragma unroll
    for (int i = 0; i < 4; ++i)
#pragma unroll
        for (int j = 0; j < 4; ++j) acc[i][j] = zero;
    float ssq = 0.0f;

    float bv0[4], bv1[4];
    bf16x8 af[4];

    // ---- prologue: A(0) first (oldest), then B(0), B(1); stage B(0) ----
    LOADA4(0, af);
    LOADB4(0, bv0);
    LOADB4(1, bv1);
    CVTW(bv0, 0);
    BARRIER();

    // ---- K loop, hand-unrolled x2; queue discipline per header comment ----
#pragma unroll 1
    for (int p = 0; p < 8; ++p) {
        {   // it = 2p: MFMA on Blds[0]; stage B(2p+1) -> Blds[1]
            MFMA16(af, 0);
            LOADA4(2 * p + 1, af);
            if (p < 7) LOADB4(2 * p + 2, bv0);
            CVTW(bv1, 1);
            BARRIER();
        }
        {   // it = 2p+1: MFMA on Blds[1]; stage B(2p+2) -> Blds[0]
            MFMA16(af, 1);
            if (p < 7) {
                LOADA4(2 * p + 2, af);
                LOADB4(2 * p + 3, bv1);
                CVTW(bv0, 0);
            }
            BARRIER();
        }
    }

    // ---- column inverse norms: 8 k-partials per column (kg groups) ----
    red[tid] = ssq;
    __syncthreads();
    if (tid < 64) {
        float s = 0.0f;
#pragma unroll
        for (int g = 0; g < 8; ++g) s += red[tid + g * 64];
        invn_s[tid] = (s > 0.0f) ? (1.0f / sqrtf(s)) : 0.0f;
    }

    // ---- fused exact label phase: each wave scans 64 rows; for labels in
    // this block's window (~0.46 per block), recompute the fp32 dot + column
    // norm + margin formula and park it in lo_s for the epilogue.
#pragma unroll 1
    for (int b = wave; b < BATCH; b += 8) {
        const int lc = lab_s[b];
        if (lc >= n0 && lc < n0 + 64) {          // wave-uniform branch
            const float* col = Kmat + lc;
            const float* e = emb + b * EMBD;
            float dot = 0.0f, ss = 0.0f;
#pragma unroll
            for (int k = lane; k < EMBD; k += 64) {
                const float kv = col[(size_t)k * CLASSNUM];
                dot = fmaf(e[k], kv, dot);
                ss  = fmaf(kv, kv, ss);
            }
            for (int off = 32; off > 0; off >>= 1) {
                dot += __shfl_down(dot, off);
                ss  += __shfl_down(ss, off);
            }
            if (lane == 0) {
                float cc = dot / sqrtf(ss);
                cc = clampf(cc, -1.0f + EPS_C, 1.0f - EPS_C);
                const float msv = msw[b];
                float th = acosf(cc) - M_C * msv;
                th = clampf(th, EPS_C, PI_F - EPS_C);
                lo_s[b] = (cosf(th) - (M_C + M_C * msv)) * S_C;
            }
        }
    }
    __syncthreads();

    // ---- epilogue: out = S * clip(cosine); label entries substituted.
    // ni innermost: 4 consecutive stores cover 256 B contiguous per row. ----
#pragma unroll
    for (int mi = 0; mi < 4; ++mi) {
#pragma unroll
        for (int rr = 0; rr < 4; ++rr) {
            const int row = wave * 64 + mi * 16 + quad * 4 + rr;
            const int labc = lab_s[row];
            const float lov = lo_s[row];
            float* orow = out + (size_t)row * CLASSNUM;
#pragma unroll
            for (int ni = 0; ni < 4; ++ni) {
                const int col_loc = ni * 16 + r16;
                const int col = n0 + col_loc;
                if (col < CLASSNUM) {
                    const float cc = clampf(acc[mi][ni][rr] * invn_s[col_loc],
                                            -1.0f + EPS_C, 1.0f - EPS_C);
                    float v = cc * S_C;
                    if (labc == col) v = lov;
                    orow[col] = v;
                }
            }
        }
    }
}

extern "C" void kernel_launch(void* const* d_in, const int* in_sizes, int n_in,
                              void* d_out, int out_size, void* d_ws, size_t ws_size,
                              hipStream_t stream)
{
    const float* emb   = (const float*)d_in[0];
    const float* norms = (const float*)d_in[1];
    const int*   label = (const int*)d_in[2];
    const float* csn   = (const float*)d_in[3];
    const float* kmat  = (const float*)d_in[4];
    float* out = (float*)d_out;

    // workspace: [A bf16 fragment-tiled 512x512 | msw 512]
    const size_t A_BYTES = (size_t)BATCH * EMBD * sizeof(bf16_t);  // 524288
    if (ws_size < A_BYTES + 4096) return;
    bf16_t* Aws = (bf16_t*)d_ws;
    float* msw  = (float*)((char*)d_ws + A_BYTES);

    prep_kernel<<<129, 256, 0, stream>>>(emb, norms, csn, Aws, msw);
    const int nblk = (CLASSNUM + 63) / 64;   // 1106
    gemm_kernel<<<nblk, 512, 0, stream>>>(Aws, kmat, emb, label, msw, out);
}